// Round 4
// baseline (231.696 us; speedup 1.0000x reference)
//
#include <hip/hip_runtime.h>

// YOLO loss reduction: B=512, 3136 cells/sample, 15 slots/cell, fp32, sum.
//
// R1 (256-thr LDS tile): FETCH 94 MB, 75 us — cross-wave barrier drain, ~11
//    waves/CU of independent progress.
// R2 (cell/thread): coalescing lost, FETCH 339 MB, 116 us.
// R3 (slot-decomposed): FETCH 95 MB but VALUBusy 64% (4 transcendentals +
//    slot decode per ELEMENT), 84 us.
// R4: single-wave workgroups + global_load_lds. Each 64-thread block stages
//    a private 64-cell tile (7.7 KB LDS) via 30 coalesced 256 B wave-loads;
//    barrier is a pure waitcnt drain (no cross-wave coupling); ~16
//    independent wave pipelines per CU hide latency via TLP. Per-cell
//    compute is the VALU minimum: 2 sqrt + 2 log per 15 elements using
//    (sqrt(a)-sqrt(b))^2 = a+b-2*sqrt(ab).

#define EPSF 1e-9f

typedef __attribute__((address_space(3))) void lds_void_t;
typedef const __attribute__((address_space(1))) void gmem_void_t;

__device__ __forceinline__ void gload_lds4(const float* g, float* l) {
    // lane i's 4 bytes land at l + i*4 (wave-uniform LDS base + lane*size)
    __builtin_amdgcn_global_load_lds((gmem_void_t*)g, (lds_void_t*)l, 4, 0, 0);
}

__device__ __forceinline__ float cell_loss(const float* __restrict__ oc,
                                           const float* __restrict__ tc) {
    const float o0 = oc[0];
    const float d0 = o0 - tc[0];
    const float ow = oc[2], tw = tc[2], oh = oc[3], th = tc[3];
    // (sqrt(a)-sqrt(b))^2 = a + b - 2*sqrt(a*b): 1 transcendental, not 2
    const float w2 = ow + tw - 2.f * sqrtf(ow * tw);
    const float h2 = oh + th - 2.f * sqrtf(oh * th);
    const float ov = oc[4], tv = tc[4];
    const float conf = -(tv * __logf(ov + EPSF)
                       + (1.f - tv) * __logf(1.f - ov + EPSF));
    float s = d0 * d0 + w2 + h2 + conf;
    #pragma unroll
    for (int k = 5; k < 14; ++k) { const float d = tc[k] - oc[k]; s += d * d; }
    return (o0 != 0.f) ? s : 0.f;
}

__global__ __launch_bounds__(64) void yolo_loss_kernel(
    const float* __restrict__ o, const float* __restrict__ t,
    float* __restrict__ out_sum, int n_cells)
{
    __shared__ float so[960];   // 64 cells x 15 floats
    __shared__ float st[960];

    const int lane = threadIdx.x;
    const int n_tiles = n_cells >> 6;

    float acc = 0.f;

    for (int tile = blockIdx.x; tile < n_tiles; tile += gridDim.x) {
        // previous iteration's ds_reads must return before DMA overwrites LDS
        __builtin_amdgcn_s_waitcnt(0xC07F);   // lgkmcnt(0) only
        __syncthreads();

        const size_t base = (size_t)tile * 960;
        const float* go = o + base + lane;
        const float* gt = t + base + lane;
        #pragma unroll
        for (int k = 0; k < 15; ++k) gload_lds4(go + k * 64, &so[k * 64]);
        #pragma unroll
        for (int k = 0; k < 15; ++k) gload_lds4(gt + k * 64, &st[k * 64]);

        // DMA completion is tracked by vmcnt — drain explicitly (single-wave
        // barriers may elide the full drain)
        __builtin_amdgcn_s_waitcnt(0x0F70);   // vmcnt(0) only
        __syncthreads();

        acc += cell_loss(so + lane * 15, st + lane * 15);
    }

    // tail cells (n_cells % 64): block 0, direct global reads (tiny)
    const int tail0 = n_tiles << 6;
    if (blockIdx.x == 0 && lane < (n_cells - tail0)) {
        const size_t c = (size_t)(tail0 + lane) * 15;
        acc += cell_loss(o + c, t + c);
    }

    // wave (64-lane) shuffle reduction -> one atomic per block
    #pragma unroll
    for (int off = 32; off; off >>= 1) acc += __shfl_down(acc, off, 64);
    if (lane == 0) atomicAdd(out_sum, acc);
}

extern "C" void kernel_launch(void* const* d_in, const int* in_sizes, int n_in,
                              void* d_out, int out_size, void* d_ws, size_t ws_size,
                              hipStream_t stream) {
    const float* o = (const float*)d_in[0];
    const float* t = (const float*)d_in[1];
    float* out = (float*)d_out;
    const int n = in_sizes[0];
    const int n_cells = n / 15;

    // d_out is poisoned 0xAA before every timed replay -> zero it on-stream.
    hipMemsetAsync(out, 0, sizeof(float), stream);

    // 16 single-wave blocks per CU; grid-stride over 64-cell tiles
    const int grid = 4096;
    yolo_loss_kernel<<<grid, 64, 0, stream>>>(o, t, out, n_cells);
}

// Round 5
// 212.559 us; speedup vs baseline: 1.0900x; 1.0900x over previous
//
#include <hip/hip_runtime.h>

// YOLO loss reduction: B=512, 3136 cells/sample, 15 slots/cell, fp32, sum.
//
// History: R1 LDS-tile 75us (barrier-drain latency); R2 cell/thread 116us
// (FETCH 339 MB, coalescing lost); R3 slot-stream 84us (FETCH 95 MB but
// VALUBusy 64% -- IEEE sqrtf lowering ~12 inst x 8/iter); R4 1-wave
// global_load_lds 95us (serial load->drain->consume, occ 32%).
//
// R5 = R3's streaming structure with the VALU gutted:
//  - __builtin_amdgcn_sqrtf: raw v_sqrt_f32 (1 inst, plenty at 2% tolerance)
//  - (sqrt(a)-sqrt(b))^2 = a+b-2*sqrt(ab): 1 sqrt/element
//  - __log2f * ln2: native v_log_f32
//  - exact-division grid (2940*256*8 float4s): guard-free unroll-4 batches,
//    8 dwordx4 + 8 L1-hit gate gathers outstanding per thread.

#define EPSF 1e-9f
#define LN2F 0.69314718055994530942f

__device__ __forceinline__ float proc4(const float4* __restrict__ o4,
                                       const float4* __restrict__ t4,
                                       const float* __restrict__ o,
                                       unsigned i)
{
    const float4 ov = o4[i];
    const float4 tv = t4[i];
    const unsigned e0    = i * 4u;
    const unsigned cell0 = e0 / 15u;          // magic-mul div
    const unsigned slot0 = e0 - cell0 * 15u;
    const unsigned cell3 = (e0 + 3u) / 15u;
    const float g_lo = o[cell0 * 15u];        // cell gate: L1-hot gather
    const float g_hi = o[cell3 * 15u];

    const float oe[4] = {ov.x, ov.y, ov.z, ov.w};
    const float te[4] = {tv.x, tv.y, tv.z, tv.w};

    float r = 0.f;
    #pragma unroll
    for (int j = 0; j < 4; ++j) {
        unsigned s = slot0 + (unsigned)j;
        const bool wrap = s >= 15u;
        s = wrap ? s - 15u : s;
        const float gate = wrap ? g_hi : g_lo;
        const float ox = oe[j], tx = te[j];

        const float d   = ox - tx;
        const float sq  = d * d;
        // (sqrt(a)-sqrt(b))^2 = a + b - 2*sqrt(a*b): one v_sqrt_f32
        const float s23 = (ox + tx) - 2.f * __builtin_amdgcn_sqrtf(ox * tx);
        // BCE: native v_log_f32 via __log2f
        const float l1  = __log2f(ox + EPSF) * LN2F;
        const float l2  = __log2f((1.f - ox) + EPSF) * LN2F;
        const float bce = -(tx * l1 + (1.f - tx) * l2);

        float c = ((s == 2u) | (s == 3u)) ? s23 : sq;
        c = (s == 4u) ? bce : c;
        c = ((s == 1u) | (s == 14u)) ? 0.f : c;
        c = (gate != 0.f) ? c : 0.f;
        r += c;
    }
    return r;
}

__global__ __launch_bounds__(256) void yolo_loss_kernel(
    const float* __restrict__ o, const float* __restrict__ t,
    float* __restrict__ out_sum, int n4, int n)
{
    const int tid = threadIdx.x;
    const unsigned total = gridDim.x * 256u;
    const unsigned idx   = blockIdx.x * 256u + (unsigned)tid;
    const float4* o4 = (const float4*)o;
    const float4* t4 = (const float4*)t;

    const unsigned iters = (unsigned)n4 / total;   // 8 for the ref shape
    const unsigned rem   = (unsigned)n4 - iters * total;

    float acc = 0.f;
    unsigned i = idx;
    #pragma unroll 4
    for (unsigned k = 0; k < iters; ++k, i += total)
        acc += proc4(o4, t4, o, i);
    if (idx < rem)
        acc += proc4(o4, t4, o, iters * total + idx);

    // scalar tail (n % 4) — zero for the ref shape; kept for generality
    const int tail0 = n4 * 4;
    if (blockIdx.x == 0 && tid < n - tail0) {
        const unsigned e = (unsigned)(tail0 + tid);
        const unsigned cell = e / 15u;
        const unsigned s = e - cell * 15u;
        const float gate = o[cell * 15u];
        const float ox = o[e], tx = t[e];
        const float d = ox - tx;
        const float sq = d * d;
        const float s23 = (ox + tx) - 2.f * __builtin_amdgcn_sqrtf(ox * tx);
        const float l1 = __log2f(ox + EPSF) * LN2F;
        const float l2 = __log2f((1.f - ox) + EPSF) * LN2F;
        const float bce = -(tx * l1 + (1.f - tx) * l2);
        float c = ((s == 2u) | (s == 3u)) ? s23 : sq;
        c = (s == 4u) ? bce : c;
        c = ((s == 1u) | (s == 14u)) ? 0.f : c;
        c = (gate != 0.f) ? c : 0.f;
        acc += c;
    }

    // wave (64-lane) shuffle reduction -> cross-wave LDS -> one atomic/block
    #pragma unroll
    for (int off = 32; off; off >>= 1) acc += __shfl_down(acc, off, 64);
    __shared__ float wsum[4];
    if ((tid & 63) == 0) wsum[tid >> 6] = acc;
    __syncthreads();
    if (tid == 0) atomicAdd(out_sum, wsum[0] + wsum[1] + wsum[2] + wsum[3]);
}

extern "C" void kernel_launch(void* const* d_in, const int* in_sizes, int n_in,
                              void* d_out, int out_size, void* d_ws, size_t ws_size,
                              hipStream_t stream) {
    const float* o = (const float*)d_in[0];
    const float* t = (const float*)d_in[1];
    float* out = (float*)d_out;
    const int n = in_sizes[0];
    const int n4 = n / 4;

    // d_out is poisoned 0xAA before every timed replay -> zero it on-stream.
    hipMemsetAsync(out, 0, sizeof(float), stream);

    // 2940 blocks: 2940*256*8 == n4 exactly for the ref shape -> uniform
    // 8 iters/thread, no guards in the unrolled body; ~11.5 blocks/CU.
    const int grid = 2940;
    yolo_loss_kernel<<<grid, 256, 0, stream>>>(o, t, out, n4, n);
}

// Round 6
// 206.427 us; speedup vs baseline: 1.1224x; 1.0297x over previous
//
#include <hip/hip_runtime.h>

// YOLO loss reduction: B=512, 3136 cells/sample, 15 slots/cell, fp32, sum.
//
// R1 LDS-tile 75us (barrier drain). R2 cell/thread 116us (FETCH 339 MB).
// R3 slot-stream 84us (VALUBusy 64%). R4 1-wave DMA 95us (serial drain).
// R5 fast-math slot-stream 76us: VALUBusy 31%, HBM 16%, VGPR=28 -> the
//    compiler kept ~2 loads in flight; latency-serialized.
// R6 = R5's memory pattern with MLP forced: all 8 iterations' loads (16
//    dwordx4 + 16 L1-hot gate gathers) issued into distinct registers up
//    front, sched_barrier(0) pins the load/compute phase split, then all
//    compute. BCE logs hoisted to once per float4 (slot-4 element select).

#define EPSF 1e-9f
#define LN2F 0.69314718055994530942f

__device__ __forceinline__ float bce_of(float ox, float tx) {
    const float l1 = __log2f(ox + EPSF);
    const float l2 = __log2f((1.f - ox) + EPSF);
    return -LN2F * (tx * l1 + (1.f - tx) * l2);
}

// ---------- fast path: every thread does exactly 8 float4s, no guards ----------
__global__ __launch_bounds__(256, 4) void yolo_loss_fast(
    const float* __restrict__ o, const float* __restrict__ t,
    float* __restrict__ out_sum)
{
    const int tid = threadIdx.x;
    const unsigned T   = gridDim.x * 256u;
    const unsigned idx = blockIdx.x * 256u + (unsigned)tid;
    const float4* o4 = (const float4*)o;
    const float4* t4 = (const float4*)t;

    // ---- phase 1: issue ALL loads (32 VMEM) into distinct registers ----
    float4 ob[8], tb[8];
    float  gl[8], gh[8];
    unsigned sl[8];
    #pragma unroll
    for (int k = 0; k < 8; ++k) {
        const unsigned i  = idx + (unsigned)k * T;
        const unsigned e0 = i * 4u;
        const unsigned c0 = e0 / 15u;          // magic-mul div
        const unsigned c3 = (e0 + 3u) / 15u;
        sl[k] = e0 - c0 * 15u;
        ob[k] = o4[i];
        tb[k] = t4[i];
        gl[k] = o[c0 * 15u];                   // gate gathers: L1-hot
        gh[k] = o[c3 * 15u];
    }
    __builtin_amdgcn_sched_barrier(0);         // nothing crosses: loads stay up front

    // ---- phase 2: all compute ----
    float acc = 0.f;
    #pragma unroll
    for (int k = 0; k < 8; ++k) {
        const unsigned s0 = sl[k];
        const float glo = gl[k], ghi = gh[k];
        const float oe[4] = {ob[k].x, ob[k].y, ob[k].z, ob[k].w};
        const float te[4] = {tb[k].x, tb[k].y, tb[k].z, tb[k].w};

        // slot-4 (confidence) element: at most one per float4 -> 1 BCE, not 4
        bool is4[4];
        #pragma unroll
        for (int j = 0; j < 4; ++j) {
            const unsigned s = s0 + (unsigned)j;
            is4[j] = (s == 4u) | (s == 19u);
        }
        float oc = oe[3], tc = te[3];
        #pragma unroll
        for (int j = 2; j >= 0; --j) { oc = is4[j] ? oe[j] : oc; tc = is4[j] ? te[j] : tc; }
        const float bce = bce_of(oc, tc);      // garbage-in-safe: inputs in (0,1)

        #pragma unroll
        for (int j = 0; j < 4; ++j) {
            unsigned s = s0 + (unsigned)j;
            const bool wrap = s >= 15u;
            s = wrap ? s - 15u : s;
            const float gate = wrap ? ghi : glo;
            const float ox = oe[j], tx = te[j];

            const float d  = ox - tx;
            const float sq = d * d;
            const float s23 = (ox + tx) - 2.f * __builtin_amdgcn_sqrtf(ox * tx);

            float c = ((s == 2u) | (s == 3u)) ? s23 : sq;
            c = is4[j] ? bce : c;
            c = ((s == 1u) | (s == 14u)) ? 0.f : c;
            c = (gate != 0.f) ? c : 0.f;
            acc += c;
        }
    }

    #pragma unroll
    for (int off = 32; off; off >>= 1) acc += __shfl_down(acc, off, 64);
    __shared__ float wsum[4];
    if ((tid & 63) == 0) wsum[tid >> 6] = acc;
    __syncthreads();
    if (tid == 0) atomicAdd(out_sum, wsum[0] + wsum[1] + wsum[2] + wsum[3]);
}

// ---------- generic fallback (any n): R5-style guarded grid-stride ----------
__global__ __launch_bounds__(256) void yolo_loss_generic(
    const float* __restrict__ o, const float* __restrict__ t,
    float* __restrict__ out_sum, int n4, int n)
{
    const int tid = threadIdx.x;
    const int stride = gridDim.x * 256;
    const float4* o4 = (const float4*)o;
    const float4* t4 = (const float4*)t;
    float acc = 0.f;

    for (int i = blockIdx.x * 256 + tid; i < n4; i += stride) {
        const float4 ov = o4[i];
        const float4 tv = t4[i];
        const unsigned e0 = (unsigned)i * 4u;
        const unsigned c0 = e0 / 15u;
        const unsigned c3 = (e0 + 3u) / 15u;
        const unsigned s0 = e0 - c0 * 15u;
        const float glo = o[c0 * 15u], ghi = o[c3 * 15u];
        const float oe[4] = {ov.x, ov.y, ov.z, ov.w};
        const float te[4] = {tv.x, tv.y, tv.z, tv.w};
        #pragma unroll
        for (int j = 0; j < 4; ++j) {
            unsigned s = s0 + (unsigned)j;
            const bool wrap = s >= 15u;
            s = wrap ? s - 15u : s;
            const float gate = wrap ? ghi : glo;
            const float ox = oe[j], tx = te[j];
            const float d = ox - tx;
            const float sq = d * d;
            const float s23 = (ox + tx) - 2.f * __builtin_amdgcn_sqrtf(ox * tx);
            float c = ((s == 2u) | (s == 3u)) ? s23 : sq;
            c = (s == 4u) ? bce_of(ox, tx) : c;
            c = ((s == 1u) | (s == 14u)) ? 0.f : c;
            c = (gate != 0.f) ? c : 0.f;
            acc += c;
        }
    }
    const int tail0 = n4 * 4;
    if (blockIdx.x == 0 && tid < n - tail0) {
        const unsigned e = (unsigned)(tail0 + tid);
        const unsigned cell = e / 15u;
        const unsigned s = e - cell * 15u;
        const float gate = o[cell * 15u];
        const float ox = o[e], tx = t[e];
        const float d = ox - tx;
        float c = d * d;
        c = ((s == 2u) | (s == 3u)) ? (ox + tx) - 2.f * __builtin_amdgcn_sqrtf(ox * tx) : c;
        c = (s == 4u) ? bce_of(ox, tx) : c;
        c = ((s == 1u) | (s == 14u)) ? 0.f : c;
        c = (gate != 0.f) ? c : 0.f;
        acc += c;
    }
    #pragma unroll
    for (int off = 32; off; off >>= 1) acc += __shfl_down(acc, off, 64);
    __shared__ float wsum[4];
    if ((tid & 63) == 0) wsum[tid >> 6] = acc;
    __syncthreads();
    if (tid == 0) atomicAdd(out_sum, wsum[0] + wsum[1] + wsum[2] + wsum[3]);
}

extern "C" void kernel_launch(void* const* d_in, const int* in_sizes, int n_in,
                              void* d_out, int out_size, void* d_ws, size_t ws_size,
                              hipStream_t stream) {
    const float* o = (const float*)d_in[0];
    const float* t = (const float*)d_in[1];
    float* out = (float*)d_out;
    const int n = in_sizes[0];
    const int n4 = n / 4;

    // d_out is poisoned 0xAA before every timed replay -> zero it on-stream.
    hipMemsetAsync(out, 0, sizeof(float), stream);

    if ((n % 4 == 0) && (n4 % (256 * 8) == 0)) {
        // ref shape: n4 = 6,021,120 -> grid 2940, exactly 8 float4s/thread
        const int grid = n4 / (256 * 8);
        yolo_loss_fast<<<grid, 256, 0, stream>>>(o, t, out);
    } else {
        yolo_loss_generic<<<2940, 256, 0, stream>>>(o, t, out, n4, n);
    }
}